// Round 1
// baseline (5903.066 us; speedup 1.0000x reference)
//
#include <hip/hip_runtime.h>

#define HID    50
#define NGATE  200      // 4*H
#define TSTEPS 512
#define DIN    5
#define NB     16       // batch elements per workgroup
#define WGS    512      // threads per workgroup

// ---- LDS layout (float offsets) ----
#define OFF_W0T   0        // [50][200]  Whh0^T                     10000
#define OFF_W1T   10000    // [100][200] [Wih1;Whh1]^T              20000
#define OFF_HT0   30000    // [50][20]   h0 transposed [k][b]        1000
#define OFF_HT1   31000    // [50][20]   h1 transposed               1000
#define OFF_C0    32000    // [16][50]                                800
#define OFF_C1    32800    // [16][50]                                800
#define OFF_GACT  33600    // [200][17]  activated gates             3400
#define OFF_XBUF  37000    // [2][16][5] double-buffered x_t          160
#define LDS_FLOATS 37160

__device__ __forceinline__ float fast_sigmoid(float x) {
    float e = __builtin_amdgcn_exp2f(-1.442695041f * x);
    return __builtin_amdgcn_rcpf(1.0f + e);
}
__device__ __forceinline__ float fast_tanh(float x) {
    // tanh(x) = 1 - 2/(exp2(2x*log2e)+1); correct limits at +-inf
    float e = __builtin_amdgcn_exp2f(2.885390082f * x);
    return 1.0f - 2.0f * __builtin_amdgcn_rcpf(1.0f + e);
}

__global__ __launch_bounds__(WGS, 1)
void lstm_fused_kernel(const float* __restrict__ x,
                       const float* __restrict__ Wih0, const float* __restrict__ Whh0,
                       const float* __restrict__ bih0, const float* __restrict__ bhh0,
                       const float* __restrict__ Wih1, const float* __restrict__ Whh1,
                       const float* __restrict__ bih1, const float* __restrict__ bhh1,
                       const float* __restrict__ Wlin, const float* __restrict__ blin,
                       float* __restrict__ out)
{
    extern __shared__ float smem[];
    float* sW0T = smem + OFF_W0T;
    float* sW1T = smem + OFF_W1T;
    float* hT0  = smem + OFF_HT0;
    float* hT1  = smem + OFF_HT1;
    float* c0s  = smem + OFF_C0;
    float* c1s  = smem + OFF_C1;
    float* gact = smem + OFF_GACT;
    float* xbuf = smem + OFF_XBUF;   // [2][NB*DIN]

    const int tid    = threadIdx.x;
    const int batch0 = blockIdx.x * NB;

    // ---- stage weights into LDS, transposed so per-k reads are stride-1 across gate lanes
    for (int i = tid; i < NGATE * HID; i += WGS) {
        int gg = i / HID, kk = i % HID;
        sW0T[kk * NGATE + gg]         = Whh0[i];
        sW1T[kk * NGATE + gg]         = Wih1[i];
        sW1T[(HID + kk) * NGATE + gg] = Whh1[i];
    }
    for (int i = tid; i < HID * 20; i += WGS) { hT0[i] = 0.0f; hT1[i] = 0.0f; }
    for (int i = tid; i < NB * HID; i += WGS) { c0s[i] = 0.0f; c1s[i] = 0.0f; }

    // stage x(t=0)  (wave 7 = tid 448..511; 80 values -> 16 threads do 2)
    if (tid >= 448) {
        int idx = tid - 448;                       // 0..63
        {
            int b = idx / DIN, d = idx % DIN;
            xbuf[b * DIN + d] = x[((size_t)(batch0 + b) * TSTEPS) * DIN + d];
        }
        if (idx < NB * DIN - 64) {                 // 16 more
            int i2 = idx + 64;
            int b = i2 / DIN, d = i2 % DIN;
            xbuf[b * DIN + d] = x[((size_t)(batch0 + b) * TSTEPS) * DIN + d];
        }
    }

    // ---- persistent per-thread gate role
    const bool dotActive = (tid < 2 * NGATE);      // 400 dot threads
    const int  g  = tid % NGATE;
    const int  b0 = (tid / NGATE) * 8;             // 0 or 8
    float bsum0 = 0.0f, bsum1 = 0.0f;
    float wx0 = 0, wx1 = 0, wx2 = 0, wx3 = 0, wx4 = 0;
    if (dotActive) {
        bsum0 = bih0[g] + bhh0[g];
        bsum1 = bih1[g] + bhh1[g];
        wx0 = Wih0[g * DIN + 0]; wx1 = Wih0[g * DIN + 1]; wx2 = Wih0[g * DIN + 2];
        wx3 = Wih0[g * DIN + 3]; wx4 = Wih0[g * DIN + 4];
    }
    const bool isSig = (g < 2 * HID) || (g >= 3 * HID);   // i,f,o sigmoid ; g tanh

    __syncthreads();

    for (int t = 0; t < TSTEPS; ++t) {
        const int par = t & 1;

        // ---- prefetch x(t+1) on the otherwise-idle wave 7
        if (tid >= 448 && t + 1 < TSTEPS) {
            int idx = tid - 448;
            {
                int b = idx / DIN, d = idx % DIN;
                xbuf[(par ^ 1) * (NB * DIN) + b * DIN + d] =
                    x[((size_t)(batch0 + b) * TSTEPS + (t + 1)) * DIN + d];
            }
            if (idx < NB * DIN - 64) {
                int i2 = idx + 64;
                int b = i2 / DIN, d = i2 % DIN;
                xbuf[(par ^ 1) * (NB * DIN) + b * DIN + d] =
                    x[((size_t)(batch0 + b) * TSTEPS + (t + 1)) * DIN + d];
            }
        }

        // ---- Phase A: layer-0 gate pre-activations + activation
        if (dotActive) {
            float acc[8];
            const float* xb = &xbuf[par * (NB * DIN)];
            #pragma unroll
            for (int b = 0; b < 8; ++b) {
                const float* xr = &xb[(b0 + b) * DIN];
                acc[b] = bsum0 + wx0 * xr[0] + wx1 * xr[1] + wx2 * xr[2]
                               + wx3 * xr[3] + wx4 * xr[4];
            }
            #pragma unroll 5
            for (int k = 0; k < HID; ++k) {
                float  w  = sW0T[k * NGATE + g];
                float4 ha = *(const float4*)&hT0[k * 20 + b0];
                float4 hb = *(const float4*)&hT0[k * 20 + b0 + 4];
                acc[0] += w * ha.x; acc[1] += w * ha.y; acc[2] += w * ha.z; acc[3] += w * ha.w;
                acc[4] += w * hb.x; acc[5] += w * hb.y; acc[6] += w * hb.z; acc[7] += w * hb.w;
            }
            #pragma unroll
            for (int b = 0; b < 8; ++b) {
                float a = isSig ? fast_sigmoid(acc[b]) : fast_tanh(acc[b]);
                gact[g * 17 + b0 + b] = a;
            }
        }
        __syncthreads();

        // ---- Phase B: layer-0 state update (800 items over 512 threads)
        {
            int b = tid / HID, j = tid % HID;
            float iv = gact[j * 17 + b];
            float fv = gact[(HID + j) * 17 + b];
            float gv = gact[(2 * HID + j) * 17 + b];
            float ov = gact[(3 * HID + j) * 17 + b];
            float c  = c0s[b * HID + j];
            c = fv * c + iv * gv;
            c0s[b * HID + j] = c;
            hT0[j * 20 + b] = ov * fast_tanh(c);
            if (tid < NB * HID - WGS) {            // 288 threads take a 2nd item
                int u2 = tid + WGS;
                int b2 = u2 / HID, j2 = u2 % HID;
                float iv2 = gact[j2 * 17 + b2];
                float fv2 = gact[(HID + j2) * 17 + b2];
                float gv2 = gact[(2 * HID + j2) * 17 + b2];
                float ov2 = gact[(3 * HID + j2) * 17 + b2];
                float c2  = c0s[b2 * HID + j2];
                c2 = fv2 * c2 + iv2 * gv2;
                c0s[b2 * HID + j2] = c2;
                hT0[j2 * 20 + b2] = ov2 * fast_tanh(c2);
            }
        }
        __syncthreads();

        // ---- Phase C: layer-1 gate pre-activations + activation
        if (dotActive) {
            float acc[8];
            #pragma unroll
            for (int b = 0; b < 8; ++b) acc[b] = bsum1;
            #pragma unroll 5
            for (int k = 0; k < HID; ++k) {        // input part: h0(t) . Wih1^T
                float  w  = sW1T[k * NGATE + g];
                float4 ha = *(const float4*)&hT0[k * 20 + b0];
                float4 hb = *(const float4*)&hT0[k * 20 + b0 + 4];
                acc[0] += w * ha.x; acc[1] += w * ha.y; acc[2] += w * ha.z; acc[3] += w * ha.w;
                acc[4] += w * hb.x; acc[5] += w * hb.y; acc[6] += w * hb.z; acc[7] += w * hb.w;
            }
            #pragma unroll 5
            for (int k = 0; k < HID; ++k) {        // recurrent part: h1(t-1) . Whh1^T
                float  w  = sW1T[(HID + k) * NGATE + g];
                float4 ha = *(const float4*)&hT1[k * 20 + b0];
                float4 hb = *(const float4*)&hT1[k * 20 + b0 + 4];
                acc[0] += w * ha.x; acc[1] += w * ha.y; acc[2] += w * ha.z; acc[3] += w * ha.w;
                acc[4] += w * hb.x; acc[5] += w * hb.y; acc[6] += w * hb.z; acc[7] += w * hb.w;
            }
            #pragma unroll
            for (int b = 0; b < 8; ++b) {
                float a = isSig ? fast_sigmoid(acc[b]) : fast_tanh(acc[b]);
                gact[g * 17 + b0 + b] = a;
            }
        }
        __syncthreads();

        // ---- Phase D: layer-1 state update
        {
            int b = tid / HID, j = tid % HID;
            float iv = gact[j * 17 + b];
            float fv = gact[(HID + j) * 17 + b];
            float gv = gact[(2 * HID + j) * 17 + b];
            float ov = gact[(3 * HID + j) * 17 + b];
            float c  = c1s[b * HID + j];
            c = fv * c + iv * gv;
            c1s[b * HID + j] = c;
            hT1[j * 20 + b] = ov * fast_tanh(c);
            if (tid < NB * HID - WGS) {
                int u2 = tid + WGS;
                int b2 = u2 / HID, j2 = u2 % HID;
                float iv2 = gact[j2 * 17 + b2];
                float fv2 = gact[(HID + j2) * 17 + b2];
                float gv2 = gact[(2 * HID + j2) * 17 + b2];
                float ov2 = gact[(3 * HID + j2) * 17 + b2];
                float c2  = c1s[b2 * HID + j2];
                c2 = fv2 * c2 + iv2 * gv2;
                c1s[b2 * HID + j2] = c2;
                hT1[j2 * 20 + b2] = ov2 * fast_tanh(c2);
            }
        }
        __syncthreads();
    }

    // ---- final linear: out[b] = W_lin . h1[b] + b_lin
    if (tid < NB) {
        float acc = blin[0];
        #pragma unroll 10
        for (int j = 0; j < HID; ++j) acc += Wlin[j] * hT1[j * 20 + tid];
        out[batch0 + tid] = acc;
    }
}

extern "C" void kernel_launch(void* const* d_in, const int* in_sizes, int n_in,
                              void* d_out, int out_size, void* d_ws, size_t ws_size,
                              hipStream_t stream) {
    (void)in_sizes; (void)n_in; (void)d_ws; (void)ws_size; (void)out_size;
    const float* x    = (const float*)d_in[0];
    const float* Wih0 = (const float*)d_in[1];
    const float* Whh0 = (const float*)d_in[2];
    const float* bih0 = (const float*)d_in[3];
    const float* bhh0 = (const float*)d_in[4];
    const float* Wih1 = (const float*)d_in[5];
    const float* Whh1 = (const float*)d_in[6];
    const float* bih1 = (const float*)d_in[7];
    const float* bhh1 = (const float*)d_in[8];
    const float* Wlin = (const float*)d_in[9];
    const float* blin = (const float*)d_in[10];
    float* out = (float*)d_out;

    dim3 grid(4096 / NB);
    dim3 block(WGS);
    size_t lds_bytes = (size_t)LDS_FLOATS * sizeof(float);
    hipLaunchKernelGGL(lstm_fused_kernel, grid, block, lds_bytes, stream,
                       x, Wih0, Whh0, bih0, bhh0,
                       Wih1, Whh1, bih1, bhh1, Wlin, blin, out);
}

// Round 2
// 659.251 us; speedup vs baseline: 8.9542x; 8.9542x over previous
//
#include <hip/hip_runtime.h>

#define TSTEPS 512
#define NB     16       // batch per workgroup
#define WGS    512      // 8 waves

typedef _Float16 f16x8 __attribute__((ext_vector_type(8)));
typedef float    f32x4 __attribute__((ext_vector_type(4)));

__device__ __forceinline__ float fast_sigmoid(float x) {
    float e = __builtin_amdgcn_exp2f(-1.442695041f * x);
    return __builtin_amdgcn_rcpf(1.0f + e);
}
__device__ __forceinline__ float fast_tanh(float x) {
    float e = __builtin_amdgcn_exp2f(2.885390082f * x);
    return 1.0f - 2.0f * __builtin_amdgcn_rcpf(1.0f + e);
}

// B row space (k) layout, per parity buffer of 8 kfrags x 64 lanes x 8 f16:
//   rows   0- 49 : h0_hi      50- 99 : h0_lo
//   rows 100-104 : x(t)      105-127 : pad (A=0)
//   rows 128-177 : h1_hi     178-227 : h1_lo   228-255 : pad (A=0)
// Layer0 B = kfrags 0-3 (A has Wih0 at k=100-104); Layer1 B = kfrags 0-7 (A=0 on x rows).

__global__ __launch_bounds__(WGS, 2)
void lstm_mfma_kernel(const float* __restrict__ x,
                      const float* __restrict__ Wih0, const float* __restrict__ Whh0,
                      const float* __restrict__ bih0, const float* __restrict__ bhh0,
                      const float* __restrict__ Wih1, const float* __restrict__ Whh1,
                      const float* __restrict__ bih1, const float* __restrict__ bhh1,
                      const float* __restrict__ Wlin, const float* __restrict__ blin,
                      float* __restrict__ out)
{
    __shared__ __align__(16) _Float16 Bbuf[2][8][64][8];
    __shared__ float h1f[NB][52];

    const int tid    = threadIdx.x;
    const int w      = tid >> 6;          // wave 0..7
    const int l      = tid & 63;
    const int sg     = l >> 4;            // 0..3 lane group
    const int bcol   = l & 15;            // batch column
    const int batch0 = blockIdx.x * NB;

    // ---- zero B space ----
    {
        int* bz = (int*)&Bbuf[0][0][0][0];       // 8192 f16 = 4096 ints
        for (int i = tid; i < 4096; i += WGS) bz[i] = 0;
    }
    __syncthreads();

    // ---- stage x(0) into parity 1 (read by phase A of t=0) ----
    const bool xact = (tid < NB * 5);
    const int  xb = tid / 5, xd = tid % 5;
    const float* xptr = x + (size_t)(batch0 + xb) * TSTEPS * 5 + xd;
    auto bwrite = [&](int par, int k, int col, _Float16 v) {
        int kf = k >> 5, kl = k & 31;
        Bbuf[par][kf][col + (((kl >> 2) & 3) << 4)][(kl & 3) | (((kl >> 4) & 1) << 2)] = v;
    };
    if (xact) bwrite(1, 100 + xd, xb, (_Float16)xptr[0]);

    // ---- gather A fragments (weights, f16) + biases into registers ----
    // frag k mapping: k = kf*32 + 4*sg + (e&3) + 16*(e>>2)  (same kappa for A and B)
    f16x8 A0[2][4], A1[2][8];
    f32x4 bia0[2], bia1[2];
    float c0[2] = {0.f, 0.f}, c1[2] = {0.f, 0.f};

    #pragma unroll
    for (int tile = 0; tile < 2; ++tile) {
        const int mt  = 2 * w + tile;
        const int gp  = mt * 16 + (l & 15);     // interleaved gate-row = j*4 + gate
        const int j   = gp >> 2;
        const int gt  = gp & 3;
        const bool real = (j < 50);
        const int row = gt * 50 + j;            // original PyTorch gate row
        #pragma unroll
        for (int kf = 0; kf < 4; ++kf) {
            f16x8 a;
            #pragma unroll
            for (int e = 0; e < 8; ++e) {
                int k = kf * 32 + 4 * sg + (e & 3) + ((e >> 2) << 4);
                float v = 0.f;
                if (real) {
                    if (k < 50)       v = Whh0[row * 50 + k];
                    else if (k < 100) v = Whh0[row * 50 + (k - 50)];
                    else if (k < 105) v = Wih0[row * 5 + (k - 100)];
                }
                a[e] = (_Float16)v;
            }
            A0[tile][kf] = a;
        }
        #pragma unroll
        for (int kf = 0; kf < 8; ++kf) {
            f16x8 a;
            #pragma unroll
            for (int e = 0; e < 8; ++e) {
                int k = kf * 32 + 4 * sg + (e & 3) + ((e >> 2) << 4);
                float v = 0.f;
                if (real) {
                    if (k < 50)                    v = Wih1[row * 50 + k];
                    else if (k < 100)              v = Wih1[row * 50 + (k - 50)];
                    else if (k >= 128 && k < 178)  v = Whh1[row * 50 + (k - 128)];
                    else if (k >= 178 && k < 228)  v = Whh1[row * 50 + (k - 178)];
                }
                a[e] = (_Float16)v;
            }
            A1[tile][kf] = a;
        }
        const int jb = mt * 4 + sg;             // this lane's hidden index (acc rows = gates 0..3)
        f32x4 b0v, b1v;
        #pragma unroll
        for (int r = 0; r < 4; ++r) {
            float v0 = 0.f, v1 = 0.f;
            if (jb < 50) {
                v0 = bih0[r * 50 + jb] + bhh0[r * 50 + jb];
                v1 = bih1[r * 50 + jb] + bhh1[r * 50 + jb];
            }
            b0v[r] = v0; b1v[r] = v1;
        }
        bia0[tile] = b0v; bia1[tile] = b1v;
    }

    const int j0 = 8 * w + sg;          // tile0 hidden index
    const int j1 = 8 * w + 4 + sg;      // tile1 hidden index

    __syncthreads();

    auto update = [&](const f32x4& acc, float& c, int j, int rbase, int par) -> float {
        float iv = fast_sigmoid(acc[0]);
        float fv = fast_sigmoid(acc[1]);
        float gv = fast_tanh(acc[2]);
        float ov = fast_sigmoid(acc[3]);
        c = fv * c + iv * gv;
        float h = ov * fast_tanh(c);
        if (j < 50) {
            _Float16 hi = (_Float16)h;
            _Float16 lo = (_Float16)(h - (float)hi);
            bwrite(par, rbase + j, bcol, hi);
            bwrite(par, rbase + 50 + j, bcol, lo);
        }
        return h;
    };

    for (int t = 0; t < TSTEPS; ++t) {
        const int p = t & 1;

        // prefetch x(t+1) early; written to LDS in phase B
        float xv = 0.f;
        if (xact && t + 1 < TSTEPS) xv = xptr[(t + 1) * 5];

        // ---- phase A: layer 0 (reads buf[p^1] kf0-3 = h0(t-1),x(t)) ----
        f32x4 a0 = bia0[0], a1 = bia0[1];
        #pragma unroll
        for (int kf = 0; kf < 4; ++kf) {
            f16x8 bf = *(const f16x8*)&Bbuf[p ^ 1][kf][l][0];
            a0 = __builtin_amdgcn_mfma_f32_16x16x32_f16(A0[0][kf], bf, a0, 0, 0, 0);
            a1 = __builtin_amdgcn_mfma_f32_16x16x32_f16(A0[1][kf], bf, a1, 0, 0, 0);
        }
        update(a0, c0[0], j0, 0, p);    // h0(t) -> buf[p] rows 0-99
        update(a1, c0[1], j1, 0, p);
        __syncthreads();

        // ---- phase B: layer 1 (reads buf[p] kf0-7 = h0(t), h1(t-1)) ----
        if (xact && t + 1 < TSTEPS) bwrite(p, 100 + xd, xb, (_Float16)xv); // x rows: A=0 in layer1, race-safe

        a0 = bia1[0]; a1 = bia1[1];
        #pragma unroll
        for (int kf = 0; kf < 8; ++kf) {
            f16x8 bf = *(const f16x8*)&Bbuf[p][kf][l][0];
            a0 = __builtin_amdgcn_mfma_f32_16x16x32_f16(A1[0][kf], bf, a0, 0, 0, 0);
            a1 = __builtin_amdgcn_mfma_f32_16x16x32_f16(A1[1][kf], bf, a1, 0, 0, 0);
        }
        {
            float h = update(a0, c1[0], j0, 128, p ^ 1);   // h1(t) -> buf[p^1] rows 128-227
            if (t == TSTEPS - 1 && j0 < 50) h1f[bcol][j0] = h;
            h = update(a1, c1[1], j1, 128, p ^ 1);
            if (t == TSTEPS - 1 && j1 < 50) h1f[bcol][j1] = h;
        }
        __syncthreads();
    }

    // ---- final linear: out[b] = Wlin . h1[b] + blin ----
    if (tid < NB) {
        float acc = blin[0];
        #pragma unroll 10
        for (int j = 0; j < 50; ++j) acc += Wlin[j] * h1f[tid][j];
        out[batch0 + tid] = acc;
    }
}

extern "C" void kernel_launch(void* const* d_in, const int* in_sizes, int n_in,
                              void* d_out, int out_size, void* d_ws, size_t ws_size,
                              hipStream_t stream) {
    (void)in_sizes; (void)n_in; (void)d_ws; (void)ws_size; (void)out_size;
    const float* x    = (const float*)d_in[0];
    const float* Wih0 = (const float*)d_in[1];
    const float* Whh0 = (const float*)d_in[2];
    const float* bih0 = (const float*)d_in[3];
    const float* bhh0 = (const float*)d_in[4];
    const float* Wih1 = (const float*)d_in[5];
    const float* Whh1 = (const float*)d_in[6];
    const float* bih1 = (const float*)d_in[7];
    const float* bhh1 = (const float*)d_in[8];
    const float* Wlin = (const float*)d_in[9];
    const float* blin = (const float*)d_in[10];
    float* out = (float*)d_out;

    dim3 grid(4096 / NB);
    dim3 block(WGS);
    hipLaunchKernelGGL(lstm_mfma_kernel, grid, block, 0, stream,
                       x, Wih0, Whh0, bih0, bhh0,
                       Wih1, Whh1, bih1, bhh1, Wlin, blin, out);
}

// Round 3
// 536.668 us; speedup vs baseline: 10.9995x; 1.2284x over previous
//
#include <hip/hip_runtime.h>

#define TSTEPS 512
#define NB     16       // batch per workgroup
#define WGS    1024     // 16 waves, 1 M-tile per wave

typedef _Float16 f16x8 __attribute__((ext_vector_type(8)));
typedef float    f32x4 __attribute__((ext_vector_type(4)));

__device__ __forceinline__ float fast_sigmoid(float x) {
    float e = __builtin_amdgcn_exp2f(-1.442695041f * x);
    return __builtin_amdgcn_rcpf(1.0f + e);
}
__device__ __forceinline__ float fast_tanh(float x) {
    float e = __builtin_amdgcn_exp2f(2.885390082f * x);
    return 1.0f - 2.0f * __builtin_amdgcn_rcpf(1.0f + e);
}

// B row space (k) per parity buffer of 8 kfrags x 64 lanes x 8 f16:
//   rows   0- 49 : h0_hi      50- 99 : h0_lo
//   rows 100-104 : x(t)      105-127 : pad (A=0)
//   rows 128-177 : h1_hi     178-227 : h1_lo   228-255 : pad (A=0)
// Layer0: B = kfrags 0-3 (Wih0 sits at k=100-104). Layer1: B = kfrags 0-7 (A=0 on x rows).
// Schedule (ONE barrier per step):
//   A(t): read buf[p^1] kf0-3, write h0(t)->buf[p] rows 0-99, write x(t+1)->buf[p] rows 100-104
//   BARRIER
//   B(t): read buf[p] kf0-7, write h1(t)->buf[p^1] rows 128-227
//   (no barrier; A(t+1) touches only regions disjoint from any wave still in B(t))

__global__ __launch_bounds__(WGS, 4)
void lstm_mfma2(const float* __restrict__ x,
                const float* __restrict__ Wih0, const float* __restrict__ Whh0,
                const float* __restrict__ bih0, const float* __restrict__ bhh0,
                const float* __restrict__ Wih1, const float* __restrict__ Whh1,
                const float* __restrict__ bih1, const float* __restrict__ bhh1,
                const float* __restrict__ Wlin, const float* __restrict__ blin,
                float* __restrict__ out)
{
    __shared__ __align__(16) _Float16 Bbuf[2][8][64][8];   // 16 KiB
    __shared__ float h1f[NB][52];

    const int tid    = threadIdx.x;
    const int w      = tid >> 6;          // wave 0..15 = M-tile
    const int l      = tid & 63;
    const int sg     = l >> 4;            // 0..3
    const int bcol   = l & 15;            // batch column
    const int batch0 = blockIdx.x * NB;

    // ---- zero B space ----
    {
        int* bz = (int*)&Bbuf[0][0][0][0];       // 8192 f16 = 4096 ints
        for (int i = tid; i < 4096; i += WGS) bz[i] = 0;
    }
    __syncthreads();

    _Float16* bbase = &Bbuf[0][0][0][0];
    auto baddr = [&](int k, int col) -> int {     // f16 index inside one parity buffer
        int kf = k >> 5, kl = k & 31;
        return (kf * 64 + col + (((kl >> 2) & 3) << 4)) * 8
               + ((kl & 3) | (((kl >> 4) & 1) << 2));
    };

    // ---- stage x(0) into parity 1 ----
    const bool xact = (tid < NB * 5);
    const int  xb = tid / 5, xd = tid % 5;
    const float* xptr = x + (size_t)(batch0 + xb) * TSTEPS * 5 + xd;
    int xadr = 0;
    if (xact) {
        xadr = baddr(100 + xd, xb);
        bbase[4096 + xadr] = (_Float16)xptr[0];
    }

    // ---- gather A fragments + biases ----
    // frag k mapping (same kappa for A and B): k = kf*32 + 4*sg + (e&3) + 16*(e>>2)
    f16x8 A0[4], A1[8];
    f32x4 bia0, bia1;
    float c0 = 0.f, c1 = 0.f;
    {
        const int gp   = w * 16 + bcol;      // interleaved gate-row = j*4 + gate
        const int jj   = gp >> 2;
        const int gt   = gp & 3;
        const bool real = (jj < 50);
        const int row  = gt * 50 + jj;       // PyTorch gate-order row
        #pragma unroll
        for (int kf = 0; kf < 4; ++kf) {
            f16x8 a;
            #pragma unroll
            for (int e = 0; e < 8; ++e) {
                int k = kf * 32 + 4 * sg + (e & 3) + ((e >> 2) << 4);
                float v = 0.f;
                if (real) {
                    if (k < 50)       v = Whh0[row * 50 + k];
                    else if (k < 100) v = Whh0[row * 50 + (k - 50)];
                    else if (k < 105) v = Wih0[row * 5 + (k - 100)];
                }
                a[e] = (_Float16)v;
            }
            A0[kf] = a;
        }
        #pragma unroll
        for (int kf = 0; kf < 8; ++kf) {
            f16x8 a;
            #pragma unroll
            for (int e = 0; e < 8; ++e) {
                int k = kf * 32 + 4 * sg + (e & 3) + ((e >> 2) << 4);
                float v = 0.f;
                if (real) {
                    if (k < 50)                    v = Wih1[row * 50 + k];
                    else if (k < 100)              v = Wih1[row * 50 + (k - 50)];
                    else if (k >= 128 && k < 178)  v = Whh1[row * 50 + (k - 128)];
                    else if (k >= 178 && k < 228)  v = Whh1[row * 50 + (k - 178)];
                }
                a[e] = (_Float16)v;
            }
            A1[kf] = a;
        }
    }
    const int j = 4 * w + sg;                // this lane's hidden index
    const bool jok = (j < 50);
    {
        f32x4 b0v, b1v;
        #pragma unroll
        for (int r = 0; r < 4; ++r) {
            float v0 = 0.f, v1 = 0.f;
            if (jok) {
                v0 = bih0[r * 50 + j] + bhh0[r * 50 + j];
                v1 = bih1[r * 50 + j] + bhh1[r * 50 + j];
            }
            b0v[r] = v0; b1v[r] = v1;
        }
        bia0 = b0v; bia1 = b1v;
    }

    // precomputed per-lane LDS write addresses (f16 index, parity adds 4096)
    int adr_h0hi = 0, adr_h0lo = 0, adr_h1hi = 0, adr_h1lo = 0;
    if (jok) {
        adr_h0hi = baddr(j, bcol);        adr_h0lo = baddr(50 + j, bcol);
        adr_h1hi = baddr(128 + j, bcol);  adr_h1lo = baddr(178 + j, bcol);
    }

    auto update = [&](const f32x4& acc, float& c, int adr_hi, int adr_lo, int par) -> float {
        float iv = fast_sigmoid(acc[0]);
        float fv = fast_sigmoid(acc[1]);
        float gv = fast_tanh(acc[2]);
        float ov = fast_sigmoid(acc[3]);
        c = fv * c + iv * gv;
        float h = ov * fast_tanh(c);
        if (jok) {
            _Float16 hi = (_Float16)h;
            _Float16 lo = (_Float16)(h - (float)hi);
            int po = par * 4096;
            bbase[po + adr_hi] = hi;
            bbase[po + adr_lo] = lo;
        }
        return h;
    };

    // x pipeline: xv_next = x(t+1), written to LDS during A(t)
    float xv_next = 0.f;
    if (xact) xv_next = xptr[5];             // x(1)
    __syncthreads();

    for (int t = 0; t < TSTEPS; ++t) {
        const int p = t & 1;

        // issue x(t+2) load early (used next iteration)
        float xv_next2 = 0.f;
        if (xact && t + 2 < TSTEPS) xv_next2 = xptr[(t + 2) * 5];

        // ---- phase A: layer 0 on buf[p^1]; write h0(t), x(t+1) into buf[p] ----
        if (xact && t + 1 < TSTEPS) bbase[p * 4096 + xadr] = (_Float16)xv_next;
        {
            f32x4 a0 = bia0;
            #pragma unroll
            for (int kf = 0; kf < 4; ++kf) {
                f16x8 bf = *(const f16x8*)&Bbuf[p ^ 1][kf][l][0];
                a0 = __builtin_amdgcn_mfma_f32_16x16x32_f16(A0[kf], bf, a0, 0, 0, 0);
            }
            update(a0, c0, adr_h0hi, adr_h0lo, p);
        }
        __syncthreads();

        // ---- phase B: layer 1 on buf[p]; write h1(t) into buf[p^1] ----
        {
            f32x4 a0 = bia1;
            #pragma unroll
            for (int kf = 0; kf < 8; ++kf) {
                f16x8 bf = *(const f16x8*)&Bbuf[p][kf][l][0];
                a0 = __builtin_amdgcn_mfma_f32_16x16x32_f16(A1[kf], bf, a0, 0, 0, 0);
            }
            float h = update(a0, c1, adr_h1hi, adr_h1lo, p ^ 1);
            if (t == TSTEPS - 1 && jok) h1f[bcol][j] = h;
        }
        xv_next = xv_next2;
    }
    __syncthreads();

    // ---- final linear ----
    if (tid < NB) {
        float acc = blin[0];
        #pragma unroll 10
        for (int jj = 0; jj < 50; ++jj) acc += Wlin[jj] * h1f[tid][jj];
        out[batch0 + tid] = acc;
    }
}

extern "C" void kernel_launch(void* const* d_in, const int* in_sizes, int n_in,
                              void* d_out, int out_size, void* d_ws, size_t ws_size,
                              hipStream_t stream) {
    (void)in_sizes; (void)n_in; (void)d_ws; (void)ws_size; (void)out_size;
    const float* x    = (const float*)d_in[0];
    const float* Wih0 = (const float*)d_in[1];
    const float* Whh0 = (const float*)d_in[2];
    const float* bih0 = (const float*)d_in[3];
    const float* bhh0 = (const float*)d_in[4];
    const float* Wih1 = (const float*)d_in[5];
    const float* Whh1 = (const float*)d_in[6];
    const float* bih1 = (const float*)d_in[7];
    const float* bhh1 = (const float*)d_in[8];
    const float* Wlin = (const float*)d_in[9];
    const float* blin = (const float*)d_in[10];
    float* out = (float*)d_out;

    dim3 grid(4096 / NB);
    dim3 block(WGS);
    hipLaunchKernelGGL(lstm_mfma2, grid, block, 0, stream,
                       x, Wih0, Whh0, bih0, bhh0,
                       Wih1, Whh1, bih1, bhh1, Wlin, blin, out);
}

// Round 4
// 482.165 us; speedup vs baseline: 12.2428x; 1.1130x over previous
//
#include <hip/hip_runtime.h>

#define TSTEPS 512
#define NB     16       // batch per workgroup
#define WGS    512      // 8 waves x 2 M-tiles each

typedef _Float16 f16x8 __attribute__((ext_vector_type(8)));
typedef _Float16 f16x2 __attribute__((ext_vector_type(2)));
typedef float    f32x4 __attribute__((ext_vector_type(4)));

#define NKF0 4          // layer0 reads kfrags 0-3  (rows 0-127)
#define NKF1 7          // layer1 reads kfrags 0-6  (rows 0-223)
#define PARF 3584       // f16 per parity buffer = 7*64*8

// K row space per parity buffer (7 kfrags x 32 rows = 224):
//   rows   0- 99 : h0 interleaved (2j = hi, 2j+1 = lo)
//   rows 100-104 : x(t)        row 105 : pad
//   rows 106-205 : h1 interleaved (106+2j = hi, 107+2j = lo)
//   rows 206-223 : pad (A = 0)
// Layer0 reads kf0-3 (A=0 on rows >=105); Layer1 reads kf0-6 (A=0 on x/pad rows).
// Weights pre-scaled: gates i,f,o rows by -log2(e); gate g rows by 2*log2(e)
//   -> sigmoid = rcp(1+exp2(acc)), tanh = 1 - 2*rcp(1+exp2(acc)).
// Schedule, ONE barrier per step:
//   A(t): read buf[p^1] kf0-3; write h0(t)->buf[p] rows 0-99, x(t+1)->buf[p] rows 100-104
//   BARRIER
//   B(t): read buf[p] kf0-6; write h1(t)->buf[p^1] rows 106-205
//   (B(t) || A(t+1) touch disjoint regions; stale-read rows are A=0-masked)

__global__ __launch_bounds__(WGS, 2)
void lstm_mfma3(const float* __restrict__ x,
                const float* __restrict__ Wih0, const float* __restrict__ Whh0,
                const float* __restrict__ bih0, const float* __restrict__ bhh0,
                const float* __restrict__ Wih1, const float* __restrict__ Whh1,
                const float* __restrict__ bih1, const float* __restrict__ bhh1,
                const float* __restrict__ Wlin, const float* __restrict__ blin,
                float* __restrict__ out)
{
    __shared__ __align__(16) _Float16 Bbuf[2][NKF1][64][8];   // 14 KiB
    __shared__ float h1f[NB][52];

    const int tid    = threadIdx.x;
    const int w      = tid >> 6;          // wave 0..7
    const int l      = tid & 63;
    const int sg     = l >> 4;            // 0..3
    const int bcol   = l & 15;            // batch column
    const int batch0 = blockIdx.x * NB;

    _Float16* bbase = &Bbuf[0][0][0][0];

    // ---- zero B space (2*PARF f16 = 3584 ints) ----
    {
        int* bz = (int*)bbase;
        for (int i = tid; i < 3584; i += WGS) bz[i] = 0;
    }
    __syncthreads();

    auto baddr = [&](int k, int col) -> int {     // f16 index inside one parity buffer
        int kf = k >> 5, kl = k & 31;
        return (kf * 64 + col + (((kl >> 2) & 3) << 4)) * 8
               + ((kl & 3) | (((kl >> 4) & 1) << 2));
    };

    // ---- stage x(0) into parity 1 ----
    const bool xact = (tid < NB * 5);
    const int  xb = tid / 5, xd = tid % 5;
    const float* xptr = x + (size_t)(batch0 + xb) * TSTEPS * 5 + xd;
    int xadr = 0;
    if (xact) {
        xadr = baddr(100 + xd, xb);
        bbase[PARF + xadr] = (_Float16)xptr[0];
    }

    // ---- gather pre-scaled A fragments + biases (one-time) ----
    // frag k mapping (same kappa for A and B): k = kf*32 + 4*sg + (e&3) + 16*(e>>2)
    f16x8 A0[2][NKF0], A1[2][NKF1];
    f32x4 bia0[2], bia1[2];
    float c00 = 0.f, c01 = 0.f, c10 = 0.f, c11 = 0.f;

    #pragma unroll
    for (int tile = 0; tile < 2; ++tile) {
        const int mt   = 2 * w + tile;
        const int arow = mt * 16 + bcol;     // interleaved gate-row = j*4 + gate
        const int jj   = arow >> 2;
        const int gt   = arow & 3;
        const bool real = (jj < 50);
        const int row  = gt * 50 + jj;       // PyTorch gate-order row
        const float s  = (gt == 2) ? 2.885390082f : -1.442695041f;
        #pragma unroll
        for (int kf = 0; kf < NKF0; ++kf) {
            f16x8 a;
            #pragma unroll
            for (int e = 0; e < 8; ++e) {
                int k = kf * 32 + 4 * sg + (e & 3) + ((e >> 2) << 4);
                float v = 0.f;
                if (real) {
                    if (k < 100)      v = Whh0[row * 50 + (k >> 1)];
                    else if (k < 105) v = Wih0[row * 5 + (k - 100)];
                }
                a[e] = (_Float16)(s * v);
            }
            A0[tile][kf] = a;
        }
        #pragma unroll
        for (int kf = 0; kf < NKF1; ++kf) {
            f16x8 a;
            #pragma unroll
            for (int e = 0; e < 8; ++e) {
                int k = kf * 32 + 4 * sg + (e & 3) + ((e >> 2) << 4);
                float v = 0.f;
                if (real) {
                    if (k < 100)                  v = Wih1[row * 50 + (k >> 1)];
                    else if (k >= 106 && k < 206) v = Whh1[row * 50 + ((k - 106) >> 1)];
                }
                a[e] = (_Float16)(s * v);
            }
            A1[tile][kf] = a;
        }
    }
    const int j0  = 8 * w + sg;              // tile0 hidden index
    const int j1  = 8 * w + 4 + sg;          // tile1 hidden index
    const bool jok0 = (j0 < 50);
    const bool jok1 = (j1 < 50);
    {
        f32x4 b0a, b0b, b1a, b1b;
        #pragma unroll
        for (int r = 0; r < 4; ++r) {
            const float sr = (r == 2) ? 2.885390082f : -1.442695041f;
            b0a[r] = jok0 ? sr * (bih0[r * 50 + j0] + bhh0[r * 50 + j0]) : 0.f;
            b0b[r] = jok1 ? sr * (bih0[r * 50 + j1] + bhh0[r * 50 + j1]) : 0.f;
            b1a[r] = jok0 ? sr * (bih1[r * 50 + j0] + bhh1[r * 50 + j0]) : 0.f;
            b1b[r] = jok1 ? sr * (bih1[r * 50 + j1] + bhh1[r * 50 + j1]) : 0.f;
        }
        bia0[0] = b0a; bia0[1] = b0b; bia1[0] = b1a; bia1[1] = b1b;
    }

    // per-lane packed (hi|lo) write addresses
    const int adrH0_0 = jok0 ? baddr(2 * j0, bcol) : 0;
    const int adrH0_1 = jok1 ? baddr(2 * j1, bcol) : 0;
    const int adrH1_0 = jok0 ? baddr(106 + 2 * j0, bcol) : 0;
    const int adrH1_1 = jok1 ? baddr(106 + 2 * j1, bcol) : 0;

    auto update = [&](const f32x4& acc, float& c, int adr, int po, bool ok) -> float {
        float iv = __builtin_amdgcn_rcpf(1.0f + __builtin_amdgcn_exp2f(acc[0]));
        float fv = __builtin_amdgcn_rcpf(1.0f + __builtin_amdgcn_exp2f(acc[1]));
        float gv = 1.0f - 2.0f * __builtin_amdgcn_rcpf(1.0f + __builtin_amdgcn_exp2f(acc[2]));
        float ov = __builtin_amdgcn_rcpf(1.0f + __builtin_amdgcn_exp2f(acc[3]));
        c = fv * c + iv * gv;
        float th = 1.0f - 2.0f * __builtin_amdgcn_rcpf(1.0f + __builtin_amdgcn_exp2f(2.885390082f * c));
        float h = ov * th;
        if (ok) {
            _Float16 hi = (_Float16)h;
            _Float16 lo = (_Float16)(h - (float)hi);
            f16x2 pk; pk[0] = hi; pk[1] = lo;
            *(f16x2*)&bbase[po + adr] = pk;
        }
        return h;
    };

    float xv_next = xact ? xptr[5] : 0.f;    // x(1)
    const _Float16* vbase = &Bbuf[0][0][l][0];
    __syncthreads();

    for (int t = 0; t < TSTEPS; ++t) {
        const int p = t & 1;

        // issue x(t+2) load early (consumed next iteration)
        float xv_next2 = (xact && t + 2 < TSTEPS) ? xptr[(t + 2) * 5] : 0.f;

        // ---- phase A: layer 0 on buf[p^1]; write h0(t), x(t+1) into buf[p] ----
        if (xact && t + 1 < TSTEPS) bbase[p * PARF + xadr] = (_Float16)xv_next;
        {
            const _Float16* rd = vbase + (p ^ 1) * PARF;
            f32x4 a0 = bia0[0], a1 = bia0[1];
            #pragma unroll
            for (int kf = 0; kf < NKF0; ++kf) {
                f16x8 bf = *(const f16x8*)(rd + kf * 512);
                a0 = __builtin_amdgcn_mfma_f32_16x16x32_f16(A0[0][kf], bf, a0, 0, 0, 0);
                a1 = __builtin_amdgcn_mfma_f32_16x16x32_f16(A0[1][kf], bf, a1, 0, 0, 0);
            }
            update(a0, c00, adrH0_0, p * PARF, jok0);
            update(a1, c01, adrH0_1, p * PARF, jok1);
        }
        __syncthreads();

        // ---- phase B: layer 1 on buf[p]; write h1(t) into buf[p^1] ----
        {
            const _Float16* rd = vbase + p * PARF;
            f32x4 a0 = bia1[0], a1 = bia1[1];
            #pragma unroll
            for (int kf = 0; kf < NKF1; ++kf) {
                f16x8 bf = *(const f16x8*)(rd + kf * 512);
                a0 = __builtin_amdgcn_mfma_f32_16x16x32_f16(A1[0][kf], bf, a0, 0, 0, 0);
                a1 = __builtin_amdgcn_mfma_f32_16x16x32_f16(A1[1][kf], bf, a1, 0, 0, 0);
            }
            float h = update(a0, c10, adrH1_0, (p ^ 1) * PARF, jok0);
            if (t == TSTEPS - 1 && jok0) h1f[bcol][j0] = h;
            h = update(a1, c11, adrH1_1, (p ^ 1) * PARF, jok1);
            if (t == TSTEPS - 1 && jok1) h1f[bcol][j1] = h;
        }
        xv_next = xv_next2;
    }
    __syncthreads();

    // ---- final linear: out[b] = Wlin . h1[b] + blin ----
    if (tid < NB) {
        float acc = blin[0];
        #pragma unroll 10
        for (int jj = 0; jj < 50; ++jj) acc += Wlin[jj] * h1f[tid][jj];
        out[batch0 + tid] = acc;
    }
}

extern "C" void kernel_launch(void* const* d_in, const int* in_sizes, int n_in,
                              void* d_out, int out_size, void* d_ws, size_t ws_size,
                              hipStream_t stream) {
    (void)in_sizes; (void)n_in; (void)d_ws; (void)ws_size; (void)out_size;
    const float* x    = (const float*)d_in[0];
    const float* Wih0 = (const float*)d_in[1];
    const float* Whh0 = (const float*)d_in[2];
    const float* bih0 = (const float*)d_in[3];
    const float* bhh0 = (const float*)d_in[4];
    const float* Wih1 = (const float*)d_in[5];
    const float* Whh1 = (const float*)d_in[6];
    const float* bih1 = (const float*)d_in[7];
    const float* bhh1 = (const float*)d_in[8];
    const float* Wlin = (const float*)d_in[9];
    const float* blin = (const float*)d_in[10];
    float* out = (float*)d_out;

    dim3 grid(4096 / NB);
    dim3 block(WGS);
    hipLaunchKernelGGL(lstm_mfma3, grid, block, 0, stream,
                       x, Wih0, Whh0, bih0, bhh0,
                       Wih1, Whh1, bih1, bhh1, Wlin, blin, out);
}

// Round 5
// 403.230 us; speedup vs baseline: 14.6395x; 1.1958x over previous
//
#include <hip/hip_runtime.h>

#define TSTEPS 512
#define NB     16        // batch per workgroup
#define NW     13        // waves = M-tiles (200 gate-rows -> 13 tiles of 16)
#define WGS    (NW * 64) // 832

typedef _Float16 f16x8 __attribute__((ext_vector_type(8)));
typedef float    f32x4 __attribute__((ext_vector_type(4)));

#define NKF0 2           // layer0 K-frags: rows 0-63
#define NKF1 4           // layer1 K-frags: rows 0-127
#define PARF 2048        // f16 per parity buffer = 4*64*8

// K row space per parity buffer (4 kfrags x 32 rows = 128), single-f16 h:
//   rows  0-49 : h0      rows 50-54 : x(t)     row 55 : pad
//   rows 56-105: h1      rows 106-127 : pad (A = 0)
// Layer0 reads kf0-1 (A=0 on rows >=55); Layer1 reads kf0-3 (A=0 on x/pad rows).
// Weights pre-scaled: gates i,f,o by -log2(e); gate g by 2*log2(e)
//   -> sigmoid = rcp(1+exp2(acc)), tanh = 1 - 2*rcp(1+exp2(acc)).
// Schedule, ONE barrier per step:
//   A(t): read buf[p^1] kf0-1; write h0(t)->buf[p] rows 0-49, x(t+1)->buf[p] rows 50-54
//   BARRIER
//   B(t): read buf[p] kf0-3; write h1(t)->buf[p^1] rows 56-105
//   (B(t) || A(t+1) regions disjoint; stale rows are A=0-masked)

__global__ __launch_bounds__(WGS)
void lstm_mfma4(const float* __restrict__ x,
                const float* __restrict__ Wih0, const float* __restrict__ Whh0,
                const float* __restrict__ bih0, const float* __restrict__ bhh0,
                const float* __restrict__ Wih1, const float* __restrict__ Whh1,
                const float* __restrict__ bih1, const float* __restrict__ bhh1,
                const float* __restrict__ Wlin, const float* __restrict__ blin,
                float* __restrict__ out)
{
    __shared__ __align__(16) _Float16 Bbuf[2][NKF1][64][8];   // 8 KiB
    __shared__ float h1f[NB][52];

    const int tid    = threadIdx.x;
    const int w      = tid >> 6;          // wave 0..12 = M-tile
    const int l      = tid & 63;
    const int sg     = l >> 4;            // 0..3
    const int bcol   = l & 15;            // batch column
    const int batch0 = blockIdx.x * NB;

    _Float16* bbase = &Bbuf[0][0][0][0];

    // ---- zero B space (2*PARF f16 = 2048 ints) ----
    {
        int* bz = (int*)bbase;
        for (int i = tid; i < 2048; i += WGS) bz[i] = 0;
    }
    __syncthreads();

    auto baddr = [&](int k, int col) -> int {     // f16 index inside one parity buffer
        int kf = k >> 5, kl = k & 31;
        return (kf * 64 + col + (((kl >> 2) & 3) << 4)) * 8
               + ((kl & 3) | (((kl >> 4) & 1) << 2));
    };

    // ---- stage x(0) into parity 1 ----
    const bool xact = (tid < NB * 5);
    const int  xb = tid / 5, xd = tid % 5;
    const float* xptr = x + (size_t)(batch0 + xb) * TSTEPS * 5 + xd;
    int xadr = 0;
    if (xact) {
        xadr = baddr(50 + xd, xb);
        bbase[PARF + xadr] = (_Float16)xptr[0];
    }

    // ---- gather pre-scaled A fragments + biases ----
    // frag k mapping (same kappa for A and B): k = kf*32 + 4*sg + (e&3) + 16*(e>>2)
    f16x8 A0[NKF0], A1[NKF1];
    f32x4 bia0, bia1;
    float c0 = 0.f, c1 = 0.f;
    {
        const int arow = w * 16 + bcol;      // interleaved gate-row = j*4 + gate
        const int jj   = arow >> 2;
        const int gt   = arow & 3;
        const bool real = (jj < 50);
        const int row  = gt * 50 + jj;       // PyTorch gate-order row
        const float s  = (gt == 2) ? 2.885390082f : -1.442695041f;
        #pragma unroll
        for (int kf = 0; kf < NKF0; ++kf) {
            f16x8 a;
            #pragma unroll
            for (int e = 0; e < 8; ++e) {
                int k = kf * 32 + 4 * sg + (e & 3) + ((e >> 2) << 4);
                float v = 0.f;
                if (real) {
                    if (k < 50)      v = Whh0[row * 50 + k];
                    else if (k < 55) v = Wih0[row * 5 + (k - 50)];
                }
                a[e] = (_Float16)(s * v);
            }
            A0[kf] = a;
        }
        #pragma unroll
        for (int kf = 0; kf < NKF1; ++kf) {
            f16x8 a;
            #pragma unroll
            for (int e = 0; e < 8; ++e) {
                int k = kf * 32 + 4 * sg + (e & 3) + ((e >> 2) << 4);
                float v = 0.f;
                if (real) {
                    if (k < 50)                  v = Wih1[row * 50 + k];
                    else if (k >= 56 && k < 106) v = Whh1[row * 50 + (k - 56)];
                }
                a[e] = (_Float16)(s * v);
            }
            A1[kf] = a;
        }
    }
    const int j   = 4 * w + sg;              // this lane's hidden index
    const bool jok = (j < 50);
    {
        f32x4 b0, b1;
        #pragma unroll
        for (int r = 0; r < 4; ++r) {
            const float sr = (r == 2) ? 2.885390082f : -1.442695041f;
            b0[r] = jok ? sr * (bih0[r * 50 + j] + bhh0[r * 50 + j]) : 0.f;
            b1[r] = jok ? sr * (bih1[r * 50 + j] + bhh1[r * 50 + j]) : 0.f;
        }
        bia0 = b0; bia1 = b1;
    }

    const int adrH0 = jok ? baddr(j, bcol) : 0;
    const int adrH1 = jok ? baddr(56 + j, bcol) : 0;

    auto update = [&](const f32x4& acc, float& c, int adr, int po) -> float {
        float iv = __builtin_amdgcn_rcpf(1.0f + __builtin_amdgcn_exp2f(acc[0]));
        float fv = __builtin_amdgcn_rcpf(1.0f + __builtin_amdgcn_exp2f(acc[1]));
        float gv = 1.0f - 2.0f * __builtin_amdgcn_rcpf(1.0f + __builtin_amdgcn_exp2f(acc[2]));
        float ov = __builtin_amdgcn_rcpf(1.0f + __builtin_amdgcn_exp2f(acc[3]));
        c = fv * c + iv * gv;
        float th = 1.0f - 2.0f * __builtin_amdgcn_rcpf(1.0f + __builtin_amdgcn_exp2f(2.885390082f * c));
        float h = ov * th;
        if (jok) bbase[po + adr] = (_Float16)h;
        return h;
    };

    float xv_next = xact ? xptr[5] : 0.f;    // x(1)
    const _Float16* vbase = &Bbuf[0][0][l][0];
    __syncthreads();

    for (int t = 0; t < TSTEPS; ++t) {
        const int p = t & 1;

        // issue x(t+2) load early (consumed next iteration)
        float xv_next2 = (xact && t + 2 < TSTEPS) ? xptr[(t + 2) * 5] : 0.f;

        // ---- phase A: layer 0 on buf[p^1]; write h0(t), x(t+1) into buf[p] ----
        if (xact && t + 1 < TSTEPS) bbase[p * PARF + xadr] = (_Float16)xv_next;
        {
            const _Float16* rd = vbase + (p ^ 1) * PARF;
            f32x4 a = bia0;
            a = __builtin_amdgcn_mfma_f32_16x16x32_f16(A0[0], *(const f16x8*)(rd), a, 0, 0, 0);
            a = __builtin_amdgcn_mfma_f32_16x16x32_f16(A0[1], *(const f16x8*)(rd + 512), a, 0, 0, 0);
            update(a, c0, adrH0, p * PARF);
        }
        __syncthreads();

        // ---- phase B: layer 1 on buf[p]; write h1(t) into buf[p^1] ----
        {
            const _Float16* rd = vbase + p * PARF;
            f32x4 a = bia1;
            #pragma unroll
            for (int kf = 0; kf < NKF1; ++kf)
                a = __builtin_amdgcn_mfma_f32_16x16x32_f16(A1[kf], *(const f16x8*)(rd + kf * 512), a, 0, 0, 0);
            float h = update(a, c1, adrH1, (p ^ 1) * PARF);
            if (t == TSTEPS - 1 && jok) h1f[bcol][j] = h;
        }
        xv_next = xv_next2;
    }
    __syncthreads();

    // ---- final linear: out[b] = Wlin . h1[b] + blin ----
    if (tid < NB) {
        float acc = blin[0];
        #pragma unroll 10
        for (int jj = 0; jj < 50; ++jj) acc += Wlin[jj] * h1f[tid][jj];
        out[batch0 + tid] = acc;
    }
}

extern "C" void kernel_launch(void* const* d_in, const int* in_sizes, int n_in,
                              void* d_out, int out_size, void* d_ws, size_t ws_size,
                              hipStream_t stream) {
    (void)in_sizes; (void)n_in; (void)d_ws; (void)ws_size; (void)out_size;
    const float* x    = (const float*)d_in[0];
    const float* Wih0 = (const float*)d_in[1];
    const float* Whh0 = (const float*)d_in[2];
    const float* bih0 = (const float*)d_in[3];
    const float* bhh0 = (const float*)d_in[4];
    const float* Wih1 = (const float*)d_in[5];
    const float* Whh1 = (const float*)d_in[6];
    const float* bih1 = (const float*)d_in[7];
    const float* bhh1 = (const float*)d_in[8];
    const float* Wlin = (const float*)d_in[9];
    const float* blin = (const float*)d_in[10];
    float* out = (float*)d_out;

    dim3 grid(4096 / NB);
    dim3 block(WGS);
    hipLaunchKernelGGL(lstm_mfma4, grid, block, 0, stream,
                       x, Wih0, Whh0, bih0, bhh0,
                       Wih1, Whh1, bih1, bhh1, Wlin, blin, out);
}

// Round 6
// 354.308 us; speedup vs baseline: 16.6609x; 1.1381x over previous
//
#include <hip/hip_runtime.h>

#define TSTEPS 512
#define NB     16        // batch per workgroup
#define NW     13        // waves = M-tiles (200 gate-rows -> 13 tiles of 16)
#define WGS    (NW * 64) // 832

typedef _Float16 f16x8 __attribute__((ext_vector_type(8)));
typedef float    f32x4 __attribute__((ext_vector_type(4)));

#define NKF  4           // kfrags per parity buffer (layer1 reads all 4, layer0 kf0-1)
#define PARF 2048        // f16 per parity buffer = 4*64*8

// K row space per parity buffer (4 kfrags x 32 rows = 128), single-f16 h:
//   rows  0-49 : h0(t)     rows 50-54 : x(t+1)    row 55 : pad
//   rows 56-105: h1(t-1)   rows 106-127 : pad (A = 0)
// Weights pre-scaled: gates i,f,o by -log2(e); gate g by 2*log2(e)
//   -> sigmoid = rcp(1+exp2(acc)), tanh = 1 - 2*rcp(1+exp2(acc)).
//
// MERGED-REGION schedule, ONE barrier per region (= per timestep):
//   region r (p=r&1): read buf[p] = {h0(r), x(r+1), h1(r-1)}  [B and A SHARE kf0-1 reads]
//     B(r):   A1 (x) kf0-3 -> h1(r)   -> buf[p^1] rows 56-105
//     A(r+1): A0 (x) kf0-1 -> h0(r+1) -> buf[p^1] rows 0-49
//     xwrite: x(r+2)                  -> buf[p^1] rows 50-54
//   BARRIER
// Reads/writes hit opposite parity buffers -> race-free; 1 barrier = recurrence minimum.
// Prologue computes A(0) from {h0(-1)=0, x(0)} staged in buf[1].

__global__ __launch_bounds__(WGS)
void lstm_mfma5(const float* __restrict__ x,
                const float* __restrict__ Wih0, const float* __restrict__ Whh0,
                const float* __restrict__ bih0, const float* __restrict__ bhh0,
                const float* __restrict__ Wih1, const float* __restrict__ Whh1,
                const float* __restrict__ bih1, const float* __restrict__ bhh1,
                const float* __restrict__ Wlin, const float* __restrict__ blin,
                float* __restrict__ out)
{
    __shared__ __align__(16) _Float16 Bbuf[2][NKF][64][8];   // 8 KiB
    __shared__ float h1f[NB][52];

    const int tid    = threadIdx.x;
    const int w      = tid >> 6;          // wave 0..12 = M-tile
    const int l      = tid & 63;
    const int sg     = l >> 4;            // 0..3
    const int bcol   = l & 15;            // batch column
    const int batch0 = blockIdx.x * NB;

    _Float16* bbase = &Bbuf[0][0][0][0];

    // ---- zero B space (2*PARF f16 = 2048 ints) ----
    {
        int* bz = (int*)bbase;
        for (int i = tid; i < 2048; i += WGS) bz[i] = 0;
    }
    __syncthreads();

    auto baddr = [&](int k, int col) -> int {     // f16 index inside one parity buffer
        int kf = k >> 5, kl = k & 31;
        return (kf * 64 + col + (((kl >> 2) & 3) << 4)) * 8
               + ((kl & 3) | (((kl >> 4) & 1) << 2));
    };

    // ---- stage x(0)->buf[1], x(1)->buf[0] ----
    const bool xact = (tid < NB * 5);
    const int  xb = tid / 5, xd = tid % 5;
    const float* xptr = x + (size_t)(batch0 + xb) * TSTEPS * 5 + xd;
    int xadr = 0;
    if (xact) {
        xadr = baddr(50 + xd, xb);
        bbase[PARF + xadr] = (_Float16)xptr[0];   // x(0) -> buf[1]
        bbase[xadr]        = (_Float16)xptr[5];   // x(1) -> buf[0]
    }

    // ---- gather pre-scaled A fragments + biases ----
    // frag k mapping (same kappa for A and B): k = kf*32 + 4*sg + (e&3) + 16*(e>>2)
    f16x8 A0[2], A1[NKF];
    f32x4 bia0, bia1;
    float c0 = 0.f, c1 = 0.f;
    {
        const int arow = w * 16 + bcol;      // interleaved gate-row = j*4 + gate
        const int jj   = arow >> 2;
        const int gt   = arow & 3;
        const bool real = (jj < 50);
        const int row  = gt * 50 + jj;       // PyTorch gate-order row
        const float s  = (gt == 2) ? 2.885390082f : -1.442695041f;
        #pragma unroll
        for (int kf = 0; kf < 2; ++kf) {
            f16x8 a;
            #pragma unroll
            for (int e = 0; e < 8; ++e) {
                int k = kf * 32 + 4 * sg + (e & 3) + ((e >> 2) << 4);
                float v = 0.f;
                if (real) {
                    if (k < 50)      v = Whh0[row * 50 + k];
                    else if (k < 55) v = Wih0[row * 5 + (k - 50)];
                }
                a[e] = (_Float16)(s * v);
            }
            A0[kf] = a;
        }
        #pragma unroll
        for (int kf = 0; kf < NKF; ++kf) {
            f16x8 a;
            #pragma unroll
            for (int e = 0; e < 8; ++e) {
                int k = kf * 32 + 4 * sg + (e & 3) + ((e >> 2) << 4);
                float v = 0.f;
                if (real) {
                    if (k < 50)                  v = Wih1[row * 50 + k];
                    else if (k >= 56 && k < 106) v = Whh1[row * 50 + (k - 56)];
                }
                a[e] = (_Float16)(s * v);
            }
            A1[kf] = a;
        }
    }
    const int j   = 4 * w + sg;              // this lane's hidden index
    const bool jok = (j < 50);
    {
        f32x4 b0, b1;
        #pragma unroll
        for (int r = 0; r < 4; ++r) {
            const float sr = (r == 2) ? 2.885390082f : -1.442695041f;
            b0[r] = jok ? sr * (bih0[r * 50 + j] + bhh0[r * 50 + j]) : 0.f;
            b1[r] = jok ? sr * (bih1[r * 50 + j] + bhh1[r * 50 + j]) : 0.f;
        }
        bia0 = b0; bia1 = b1;
    }

    const int adrH0 = jok ? baddr(j, bcol) : 0;
    const int adrH1 = jok ? baddr(56 + j, bcol) : 0;

    auto update = [&](const f32x4& acc, float& c, int wadr) -> float {
        float iv = __builtin_amdgcn_rcpf(1.0f + __builtin_amdgcn_exp2f(acc[0]));
        float fv = __builtin_amdgcn_rcpf(1.0f + __builtin_amdgcn_exp2f(acc[1]));
        float gv = 1.0f - 2.0f * __builtin_amdgcn_rcpf(1.0f + __builtin_amdgcn_exp2f(acc[2]));
        float ov = __builtin_amdgcn_rcpf(1.0f + __builtin_amdgcn_exp2f(acc[3]));
        c = fv * c + iv * gv;
        float th = 1.0f - 2.0f * __builtin_amdgcn_rcpf(1.0f + __builtin_amdgcn_exp2f(2.885390082f * c));
        float h = ov * th;
        if (jok) bbase[wadr] = (_Float16)h;
        return h;
    };

    const _Float16* vbase = &Bbuf[0][0][l][0];
    __syncthreads();

    // ---- prologue: A(0) on buf[1] {h0(-1)=0, x(0)}; write h0(0) -> buf[0] ----
    {
        const _Float16* rd = vbase + PARF;
        f32x4 a = bia0;
        a = __builtin_amdgcn_mfma_f32_16x16x32_f16(A0[0], *(const f16x8*)(rd), a, 0, 0, 0);
        a = __builtin_amdgcn_mfma_f32_16x16x32_f16(A0[1], *(const f16x8*)(rd + 512), a, 0, 0, 0);
        update(a, c0, adrH0);                 // wo = 0 -> buf[0]
    }
    float xv_next = xact ? xptr[10] : 0.f;    // x(2)
    __syncthreads();

    // ---- main loop: one region per timestep, unrolled x2 for constant parity ----
#define REGION(PAR, T)                                                           \
    {                                                                            \
        const _Float16* rd = vbase + (PAR) * PARF;                               \
        const int wo = ((PAR) ^ 1) * PARF;                                       \
        f16x8 bf0 = *(const f16x8*)(rd);                                         \
        f16x8 bf1 = *(const f16x8*)(rd + 512);                                   \
        f16x8 bf2 = *(const f16x8*)(rd + 1024);                                  \
        f16x8 bf3 = *(const f16x8*)(rd + 1536);                                  \
        if (xact && (T) + 2 < TSTEPS) bbase[wo + xadr] = (_Float16)xv_next;      \
        float xv2 = (xact && (T) + 3 < TSTEPS) ? xptr[((T) + 3) * 5] : 0.f;      \
        f32x4 aB = bia1;                                                         \
        aB = __builtin_amdgcn_mfma_f32_16x16x32_f16(A1[0], bf0, aB, 0, 0, 0);    \
        aB = __builtin_amdgcn_mfma_f32_16x16x32_f16(A1[1], bf1, aB, 0, 0, 0);    \
        aB = __builtin_amdgcn_mfma_f32_16x16x32_f16(A1[2], bf2, aB, 0, 0, 0);    \
        aB = __builtin_amdgcn_mfma_f32_16x16x32_f16(A1[3], bf3, aB, 0, 0, 0);    \
        f32x4 aA = bia0;                                                         \
        aA = __builtin_amdgcn_mfma_f32_16x16x32_f16(A0[0], bf0, aA, 0, 0, 0);    \
        aA = __builtin_amdgcn_mfma_f32_16x16x32_f16(A0[1], bf1, aA, 0, 0, 0);    \
        float h1v = update(aB, c1, wo + adrH1);                                  \
        update(aA, c0, wo + adrH0);                                              \
        if ((T) == TSTEPS - 1 && jok) h1f[bcol][j] = h1v;                        \
        xv_next = xv2;                                                           \
        __syncthreads();                                                         \
    }

    for (int t = 0; t < TSTEPS; t += 2) {
        REGION(0, t)
        REGION(1, t + 1)
    }
#undef REGION

    // ---- final linear: out[b] = Wlin . h1[b] + blin ----
    if (tid < NB) {
        float acc = blin[0];
        #pragma unroll 10
        for (int jj = 0; jj < 50; ++jj) acc += Wlin[jj] * h1f[tid][jj];
        out[batch0 + tid] = acc;
    }
}

extern "C" void kernel_launch(void* const* d_in, const int* in_sizes, int n_in,
                              void* d_out, int out_size, void* d_ws, size_t ws_size,
                              hipStream_t stream) {
    (void)in_sizes; (void)n_in; (void)d_ws; (void)ws_size; (void)out_size;
    const float* x    = (const float*)d_in[0];
    const float* Wih0 = (const float*)d_in[1];
    const float* Whh0 = (const float*)d_in[2];
    const float* bih0 = (const float*)d_in[3];
    const float* bhh0 = (const float*)d_in[4];
    const float* Wih1 = (const float*)d_in[5];
    const float* Whh1 = (const float*)d_in[6];
    const float* bih1 = (const float*)d_in[7];
    const float* bhh1 = (const float*)d_in[8];
    const float* Wlin = (const float*)d_in[9];
    const float* blin = (const float*)d_in[10];
    float* out = (float*)d_out;

    dim3 grid(4096 / NB);
    dim3 block(WGS);
    hipLaunchKernelGGL(lstm_mfma5, grid, block, 0, stream,
                       x, Wih0, Whh0, bih0, bhh0,
                       Wih1, Whh1, bih1, bhh1, Wlin, blin, out);
}